// Round 3
// baseline (34.384 us; speedup 1.0000x reference)
//
#include <hip/hip_runtime.h>

// SNN 2->8->8->1, 16 steps, leak=0.8, thr=0.5.
// R14 = full-VALU loop: NO LDS in the time loop at all.
//
// Evidence chain:
//  R11 25.2us; R12 (half-VALU, 64-VGPR cap) 32.7us; R13 (dbuf) 26.4us.
//  R13's null => LDS pipe is THROUGHPUT-saturated, not latency-bound:
//  data-dependent gather (bC*9+j) has random banks -> ~5-6 distinct
//  addrs/bank -> ~2x conflict cost (~11 cyc/read) -> loop LDS work
//  ~21us/CU, the real floor under 25.2. R12's regression re-attributed
//  to reg pressure: hoisted floats under launch_bounds(256,8)'s 64-VGPR
//  cap -> spills (R12's VALU math itself passed absmax 0.0).
// Fix: all 8 dv rows + out-dot in-register (R12-verified op sequences),
// launch_bounds(256,4) -> 128-VGPR cap, no spill (est ~100). lut2/luto
// deleted; LDS = Tv only. Predicted 25.2 -> ~19us (17-21).
// If >=25us: LDS theory dead, revert to R11 base, attack VALU count.
//
// Bit-exactness invariants (absmax 0.0 R1-R13, preserved):
//  - contract(off): a*b + c stays mul+add everywhere
//  - dv_j: ascending-k fma chain from 0.f, bits in {0.0,1.0} — identical
//    op sequence the lut2 entries were built with (R12: absmax 0.0)
//  - out-dot: ascending-k fma chain from 0.f over bf2 — identical to
//    luto construction (R12: absmax 0.0)
//  - reset (m>=0.5 ? 0 : m) == m*(1-s) bitwise
//  - in-step output update: register-only, same op order as lagged form
//  - L1 exactly periodic; F = 1 + #{t: c < B_t}, B_t constexpr bit-search
//  - unified LSB convention: neuron k = bit k everywhere

// ---- compile-time breakpoint search (bit-exact f32, IEEE RN per op) ----
constexpr bool spikes_by(float c, int p) {
    float m = 0.f;
    for (int t = 0; t < p; ++t) {
        float a = 0.8f * m;
        m = a + c;
        if (m >= 0.5f) return true;
    }
    return false;
}
constexpr unsigned find_B(int p) {
    unsigned lo = 0x3D4CCCCDu;  // 0.05f: never spikes
    unsigned hi = 0x3F19999Au;  // 0.6f : spikes at step 1
    while (hi - lo > 1u) {
        unsigned mid = lo + (hi - lo) / 2u;
        if (spikes_by(__builtin_bit_cast(float, mid), p)) hi = mid;
        else lo = mid;
    }
    return hi;
}
constexpr float kB[17] = {
    0.f,
    __builtin_bit_cast(float, find_B(1)),  __builtin_bit_cast(float, find_B(2)),
    __builtin_bit_cast(float, find_B(3)),  __builtin_bit_cast(float, find_B(4)),
    __builtin_bit_cast(float, find_B(5)),  __builtin_bit_cast(float, find_B(6)),
    __builtin_bit_cast(float, find_B(7)),  __builtin_bit_cast(float, find_B(8)),
    __builtin_bit_cast(float, find_B(9)),  __builtin_bit_cast(float, find_B(10)),
    __builtin_bit_cast(float, find_B(11)), __builtin_bit_cast(float, find_B(12)),
    __builtin_bit_cast(float, find_B(13)), __builtin_bit_cast(float, find_B(14)),
    __builtin_bit_cast(float, find_B(15)), __builtin_bit_cast(float, find_B(16))
};
constexpr unsigned mk_train(int F) {
    unsigned tr = 0;
    if (F <= 16) for (int t = F; t <= 16; t += F) tr |= 1u << (t - 1);
    return tr;
}
constexpr unsigned kTv[18] = {
    0, mk_train(1), mk_train(2),  mk_train(3),  mk_train(4),  mk_train(5),
    mk_train(6),  mk_train(7),  mk_train(8),  mk_train(9),  mk_train(10),
    mk_train(11), mk_train(12), mk_train(13), mk_train(14), mk_train(15),
    mk_train(16), mk_train(17)
};

__device__ __forceinline__ unsigned long long tr8(unsigned long long x) {
    unsigned long long t;
    t = (x ^ (x >> 7))  & 0x00AA00AA00AA00AAull; x = x ^ t ^ (t << 7);
    t = (x ^ (x >> 14)) & 0x0000CCCC0000CCCCull; x = x ^ t ^ (t << 14);
    t = (x ^ (x >> 28)) & 0x00000000F0F0F0F0ull; x = x ^ t ^ (t << 28);
    return x;
}

__global__ __launch_bounds__(256, 4) void snn_kernel(
    const float* __restrict__ x,
    const float* __restrict__ W_ih, const float* __restrict__ b_ih,
    const float* __restrict__ W_hh, const float* __restrict__ b_hh,
    const float* __restrict__ W_ho, const float* __restrict__ b_ho,
    float* __restrict__ out, int n)
{
#pragma clang fp contract(off)
    __shared__ unsigned Tv[18];

    const int p = threadIdx.x;
    if (p < 18) Tv[p] = kTv[p];
    __syncthreads();

    const int i = blockIdx.x * 256 + p;
    if (i >= n) return;

    // Uniform weights: literal indices off uniform pointers -> s_load;
    // under the 128-VGPR cap even a VGPR fallback fits without spill.
    float wh[8][8];
#pragma unroll
    for (int j = 0; j < 8; ++j)
#pragma unroll
        for (int k = 0; k < 8; ++k)
            wh[j][k] = W_hh[8 * j + k];
    float wo[8];
#pragma unroll
    for (int k = 0; k < 8; ++k) wo[k] = W_ho[k];
    float bh[8];
#pragma unroll
    for (int j = 0; j < 8; ++j) bh[j] = b_hh[j];
    const float bho = b_ho[0];

    const float2 xv = reinterpret_cast<const float2*>(x)[i];
    float cur[8];
#pragma unroll
    for (int j = 0; j < 8; ++j) {
        float d = __fmaf_rn(xv.y, W_ih[2 * j + 1], __fmul_rn(xv.x, W_ih[2 * j]));
        cur[j] = __fadd_rn(d, b_ih[j]);
    }

    // F = 1 + #{t: c < B_t}; B_t compile-time literals. train = Tv[F]
    unsigned trn[8];
#pragma unroll
    for (int j = 0; j < 8; ++j) {
        float c = cur[j];
        unsigned cnt = 0;
#pragma unroll
        for (int t = 1; t <= 16; ++t)
            cnt += (c < kB[t]) ? 1u : 0u;
        trn[j] = Tv[cnt + 1u];
    }

    // 8x16 bit transpose -> step bytes (byte t = step t, bit j = neuron j)
    unsigned long long A = 0, A2 = 0;
#pragma unroll
    for (int j = 0; j < 8; ++j) {
        A  |= (unsigned long long)(trn[j] & 0xFFu) << (8 * j);
        A2 |= (unsigned long long)((trn[j] >> 8) & 0xFFu) << (8 * j);
    }
    A = tr8(A); A2 = tr8(A2);

    float m2[8] = {0.f,0.f,0.f,0.f,0.f,0.f,0.f,0.f};
    float mo = 0.f;
    unsigned tot = 0;

#pragma unroll 1
    for (int t = 0; t < 16; ++t) {
        const unsigned bC = (unsigned)A & 0xFFu;
        A = (A >> 8) | (A2 << 56); A2 >>= 8;

        // L1 spike bits as exact {0.0f, 1.0f}
        float bf[8];
#pragma unroll
        for (int k = 0; k < 8; ++k) bf[k] = (float)((bC >> k) & 1u);

        // dv_j = ascending-k fma chain (== old lut2 construction), then
        // L2 membrane update; spike bits for the output dot.
        float bf2[8];
#pragma unroll
        for (int j = 0; j < 8; ++j) {
            float acc = 0.f;
#pragma unroll
            for (int k = 0; k < 8; ++k)
                acc = __fmaf_rn(bf[k], wh[j][k], acc);
            float m = __fadd_rn(__fadd_rn(__fmul_rn(0.8f, m2[j]), acc), bh[j]);
            bool s = (m >= 0.5f);
            bf2[j] = s ? 1.0f : 0.0f;
            m2[j] = s ? 0.f : m;
        }

        // output dot: ascending-k chain (== old luto construction)
        float od = 0.f;
#pragma unroll
        for (int k = 0; k < 8; ++k)
            od = __fmaf_rn(bf2[k], wo[k], od);

        // output neuron update (register-only, in-step)
        float m = __fadd_rn(__fadd_rn(__fmul_rn(0.8f, mo), od), bho);
        bool s = (m >= 0.5f);
        tot += s ? 1u : 0u;
        mo = s ? 0.f : m;
    }

    out[i] = __fmul_rn((float)tot, 0.0625f);
}

extern "C" void kernel_launch(void* const* d_in, const int* in_sizes, int n_in,
                              void* d_out, int out_size, void* d_ws, size_t ws_size,
                              hipStream_t stream) {
    const float* x    = (const float*)d_in[0];
    const float* W_ih = (const float*)d_in[1];
    const float* b_ih = (const float*)d_in[2];
    const float* W_hh = (const float*)d_in[3];
    const float* b_hh = (const float*)d_in[4];
    const float* W_ho = (const float*)d_in[5];
    const float* b_ho = (const float*)d_in[6];
    float* out = (float*)d_out;

    const int n = out_size;  // 524288
    const int block = 256;
    const int grid = (n + block - 1) / block;  // 2048
    snn_kernel<<<grid, block, 0, stream>>>(x, W_ih, b_ih, W_hh, b_hh,
                                           W_ho, b_ho, out, n);
}

// Round 4
// 25.385 us; speedup vs baseline: 1.3545x; 1.3545x over previous
//
#include <hip/hip_runtime.h>

// SNN 2->8->8->1, 16 steps, leak=0.8, thr=0.5.
// R15 = R11 with the DS pipeline made REAL: distance-2 dv prefetch +
// full 16-step unroll + wait-friendly DS issue ordering.
//
// Evidence chain: R11 25.2 | R12 32.7 (VALU+spill) | R13 26.4 (dbuf null)
// | R14 34.4 (full VALU+spill). Sum-model fits R11 exactly:
// VALU ~1136 + LDS ~2000 cyc/step/CU = 3240 observed -> pipes serialized.
// Root cause of R13's null: lgkmcnt is IN-ORDER for DS ops, and the
// luto[mk2] read was issued BEFORE the dv prefetch -> consuming dv
// requires draining the newest DS op (lgkmcnt(0)) -> prefetch dead.
// R15 body order: [consume dv_t | issue dv_{t+2} | mo-update (od_{t-1})
// | issue luto_t]  =>  every consume waits lgkmcnt(9)/(8) on data issued
// a full iteration earlier; no drains; pipes overlap (sum -> max).
// Full unroll: byte = 1 compile-time v_bfe (kills serial shift-register,
// ~8 VALU/step), no junk prefetches at t=14/15, dv[2][8] static-indexed.
// Predicted: 25.2 -> ~17-20us. If >=24.5: loop is LDS-throughput-bound
// (conflicts ~2x) -> next: entry-placement permutation / ds_read2.
//
// Bit-exactness invariants (absmax 0.0 R1-R14, preserved):
//  - contract(off): a*b + c stays mul+add everywhere
//  - dots: ascending-k fma chain from 0, s in {0,1} (== plain-add accum)
//  - m2 updates independent across j -> descending-j order bitwise same;
//    mk2 = 2*mk2+s descending == |= s<<j ascending
//  - reset (m>=0.5 ? 0 : m) == m*(1-s) bitwise
//  - od_{t-1} consume order identical to R11's lagged outdot
//  - L1 exactly periodic; F = 1 + #{t: c < B_t}, B_t constexpr bit-search
//  - unified LSB convention: neuron k = bit k in lut2/luto/mask/transpose

// ---- compile-time breakpoint search (bit-exact f32, IEEE RN per op) ----
constexpr bool spikes_by(float c, int p) {
    float m = 0.f;
    for (int t = 0; t < p; ++t) {
        float a = 0.8f * m;
        m = a + c;
        if (m >= 0.5f) return true;
    }
    return false;
}
constexpr unsigned find_B(int p) {
    unsigned lo = 0x3D4CCCCDu;  // 0.05f: never spikes
    unsigned hi = 0x3F19999Au;  // 0.6f : spikes at step 1
    while (hi - lo > 1u) {
        unsigned mid = lo + (hi - lo) / 2u;
        if (spikes_by(__builtin_bit_cast(float, mid), p)) hi = mid;
        else lo = mid;
    }
    return hi;
}
constexpr float kB[17] = {
    0.f,
    __builtin_bit_cast(float, find_B(1)),  __builtin_bit_cast(float, find_B(2)),
    __builtin_bit_cast(float, find_B(3)),  __builtin_bit_cast(float, find_B(4)),
    __builtin_bit_cast(float, find_B(5)),  __builtin_bit_cast(float, find_B(6)),
    __builtin_bit_cast(float, find_B(7)),  __builtin_bit_cast(float, find_B(8)),
    __builtin_bit_cast(float, find_B(9)),  __builtin_bit_cast(float, find_B(10)),
    __builtin_bit_cast(float, find_B(11)), __builtin_bit_cast(float, find_B(12)),
    __builtin_bit_cast(float, find_B(13)), __builtin_bit_cast(float, find_B(14)),
    __builtin_bit_cast(float, find_B(15)), __builtin_bit_cast(float, find_B(16))
};
constexpr unsigned mk_train(int F) {
    unsigned tr = 0;
    if (F <= 16) for (int t = F; t <= 16; t += F) tr |= 1u << (t - 1);
    return tr;
}
constexpr unsigned kTv[18] = {
    0, mk_train(1), mk_train(2),  mk_train(3),  mk_train(4),  mk_train(5),
    mk_train(6),  mk_train(7),  mk_train(8),  mk_train(9),  mk_train(10),
    mk_train(11), mk_train(12), mk_train(13), mk_train(14), mk_train(15),
    mk_train(16), mk_train(17)
};

__device__ __forceinline__ unsigned long long tr8(unsigned long long x) {
    unsigned long long t;
    t = (x ^ (x >> 7))  & 0x00AA00AA00AA00AAull; x = x ^ t ^ (t << 7);
    t = (x ^ (x >> 14)) & 0x0000CCCC0000CCCCull; x = x ^ t ^ (t << 14);
    t = (x ^ (x >> 28)) & 0x00000000F0F0F0F0ull; x = x ^ t ^ (t << 28);
    return x;
}

__global__ __launch_bounds__(256, 8) void snn_kernel(
    const float* __restrict__ x,
    const float* __restrict__ W_ih, const float* __restrict__ b_ih,
    const float* __restrict__ W_hh, const float* __restrict__ b_hh,
    const float* __restrict__ W_ho, const float* __restrict__ b_ho,
    float* __restrict__ out, int n)
{
#pragma clang fp contract(off)
    __shared__ float lut2[256 * 9];   // 9 KB, stride 9 (odd -> bank spread)
    __shared__ float luto[256];       // 1 KB
    __shared__ unsigned Tv[18];

    const int p = threadIdx.x;

    {   // lut2 + luto: entry q, neuron k at bit k (LSB), exact fma chains
        float bits[8];
#pragma unroll
        for (int k = 0; k < 8; ++k) bits[k] = (float)((p >> k) & 1);
#pragma unroll
        for (int j = 0; j < 8; ++j) {
            float acc = 0.f;
#pragma unroll
            for (int k = 0; k < 8; ++k)
                acc = __fmaf_rn(bits[k], W_hh[8 * j + k], acc);
            lut2[p * 9 + j] = acc;    // conflict-free: (9p+j) mod 32 spreads
        }
        float acc = 0.f;
#pragma unroll
        for (int k = 0; k < 8; ++k)
            acc = __fmaf_rn(bits[k], W_ho[k], acc);
        luto[p] = acc;
    }
    if (p < 18) Tv[p] = kTv[p];
    __syncthreads();

    const int i = blockIdx.x * 256 + p;
    if (i >= n) return;

    const float2 xv = reinterpret_cast<const float2*>(x)[i];
    float cur[8];
#pragma unroll
    for (int j = 0; j < 8; ++j) {
        float d = __fmaf_rn(xv.y, W_ih[2 * j + 1], __fmul_rn(xv.x, W_ih[2 * j]));
        cur[j] = __fadd_rn(d, b_ih[j]);
    }

    // F = 1 + #{t: c < B_t}; B_t compile-time literals. train = Tv[F]
    unsigned trn[8];
#pragma unroll
    for (int j = 0; j < 8; ++j) {
        float c = cur[j];
        unsigned cnt = 0;
#pragma unroll
        for (int t = 1; t <= 16; ++t)
            cnt += (c < kB[t]) ? 1u : 0u;
        trn[j] = Tv[cnt + 1u];
    }

    // 8x16 bit transpose -> step bytes (byte t = step t, bit j = neuron j)
    unsigned long long A = 0, A2 = 0;
#pragma unroll
    for (int j = 0; j < 8; ++j) {
        A  |= (unsigned long long)(trn[j] & 0xFFu) << (8 * j);
        A2 |= (unsigned long long)((trn[j] >> 8) & 0xFFu) << (8 * j);
    }
    A = tr8(A); A2 = tr8(A2);

    float bh[8];
#pragma unroll
    for (int j = 0; j < 8; ++j) bh[j] = b_hh[j];
    const float bho = b_ho[0];

    float m2[8] = {0.f,0.f,0.f,0.f,0.f,0.f,0.f,0.f};
    float mo = 0.f, odP = 0.f;
    unsigned tot = 0;

    float dv[2][8];

    // prologue: issue dv_0, dv_1 (bytes 0,1; compile-time bfe extracts)
    {
        const unsigned b0 = (unsigned)(A) & 0xFFu;
        const float* e0 = &lut2[b0 * 9];
#pragma unroll
        for (int j = 0; j < 8; ++j) dv[0][j] = e0[j];
        const unsigned b1 = (unsigned)(A >> 8) & 0xFFu;
        const float* e1 = &lut2[b1 * 9];
#pragma unroll
        for (int j = 0; j < 8; ++j) dv[1][j] = e1[j];
    }

    // fully unrolled 16-step pipeline, distance-2 dv prefetch.
    // body t: [consume dv_t | issue dv_{t+2} | mo-update(od_{t-1}) |
    //          issue luto_t]  -> counted lgkmcnt(9)/(8), no drains.
#pragma unroll
    for (int t = 0; t < 16; ++t) {
        // consume dv_t (issued 2 bodies ago; 9 newer DS ops outstanding)
        unsigned mk2 = 0;
#pragma unroll
        for (int j = 7; j >= 0; --j) {
            float m = __fadd_rn(__fadd_rn(__fmul_rn(0.8f, m2[j]), dv[t & 1][j]), bh[j]);
            bool s = (m >= 0.5f);
            mk2 = 2u * mk2 + (s ? 1u : 0u);
            m2[j] = s ? 0.f : m;
        }

        // issue dv_{t+2} into the buffer just consumed
        if (t + 2 < 16) {
            const int tn = t + 2;
            const unsigned bN = (tn < 8)
                ? ((unsigned)(A  >> (8 * tn)) & 0xFFu)
                : ((unsigned)(A2 >> (8 * (tn - 8))) & 0xFFu);
            const float* en = &lut2[bN * 9];
#pragma unroll
            for (int j = 0; j < 8; ++j) dv[t & 1][j] = en[j];
        }

        // mo-update for step t-1 (consumes od_{t-1}, issued one body ago;
        // 8 newer DS ops outstanding -> counted wait, no drain)
        if (t > 0) {
            float m = __fadd_rn(__fadd_rn(__fmul_rn(0.8f, mo), odP), bho);
            bool s = (m >= 0.5f);
            tot += s ? 1u : 0u;
            mo = s ? 0.f : m;
        }

        // issue luto_t (consumed in body t+1)
        odP = luto[mk2];
    }
    {   // epilogue: output update for step 15
        float m = __fadd_rn(__fadd_rn(__fmul_rn(0.8f, mo), odP), bho);
        tot += (m >= 0.5f) ? 1u : 0u;
    }

    out[i] = __fmul_rn((float)tot, 0.0625f);
}

extern "C" void kernel_launch(void* const* d_in, const int* in_sizes, int n_in,
                              void* d_out, int out_size, void* d_ws, size_t ws_size,
                              hipStream_t stream) {
    const float* x    = (const float*)d_in[0];
    const float* W_ih = (const float*)d_in[1];
    const float* b_ih = (const float*)d_in[2];
    const float* W_hh = (const float*)d_in[3];
    const float* b_hh = (const float*)d_in[4];
    const float* W_ho = (const float*)d_in[5];
    const float* b_ho = (const float*)d_in[6];
    float* out = (float*)d_out;

    const int n = out_size;  // 524288
    const int block = 256;
    const int grid = (n + block - 1) / block;  // 2048
    snn_kernel<<<grid, block, 0, stream>>>(x, W_ih, b_ih, W_hh, b_hh,
                                           W_ho, b_ho, out, n);
}

// Round 5
// 25.246 us; speedup vs baseline: 1.3620x; 1.0055x over previous
//
#include <hip/hip_runtime.h>

// SNN 2->8->8->1, 16 steps, leak=0.8, thr=0.5.
// R16 = R15 with the dv gather read as 2x ds_read_b128 (stride-12 lut).
//
// Evidence chain: R11 25.2 | R12 32.7 | R13 26.4 | R14 34.4 | R15 25.4.
// R11==R13==R15 (same DS work, three different schedules) => schedule
// is irrelevant; the floor is DS-pipe THROUGHPUT. m134: per-instr cost
// dominates (b32 5.8 cyc = 5.8 cyc/word; b128 12 cyc = 3 cyc/word).
// So cut DS instrs/step 9 -> 3: each 8-float entry = 2x b128.
// Conflict design: stride 12 floats (48 B). A b128 touches a 4-word
// window at 12b mod 32; as b mod 8 varies this hits ALL 8 window
// positions bijectively -> random bytes spread uniformly (~8 lanes per
// position = conflict-free floor). 16B alignment: 48 % 16 == 0.
// VALU and registers untouched (clean DS-only experiment, unlike R12).
// Predicted: 25.4 -> ~19-21us. If >=24.5: DS-throughput theory dead,
// next round bisects with a timing skeleton.
//
// Bit-exactness invariants (absmax 0.0 R1-R15, preserved):
//  - contract(off): a*b + c stays mul+add everywhere
//  - dots: ascending-k fma chain from 0, s in {0,1} (== plain-add accum)
//  - m2 updates independent across j -> descending-j order bitwise same;
//    mk2 = 2*mk2+s descending == |= s<<j ascending
//  - reset (m>=0.5 ? 0 : m) == m*(1-s) bitwise
//  - wider LDS reads return identical bits
//  - L1 exactly periodic; F = 1 + #{t: c < B_t}, B_t constexpr bit-search
//  - unified LSB convention: neuron k = bit k in lut2/luto/mask/transpose

// ---- compile-time breakpoint search (bit-exact f32, IEEE RN per op) ----
constexpr bool spikes_by(float c, int p) {
    float m = 0.f;
    for (int t = 0; t < p; ++t) {
        float a = 0.8f * m;
        m = a + c;
        if (m >= 0.5f) return true;
    }
    return false;
}
constexpr unsigned find_B(int p) {
    unsigned lo = 0x3D4CCCCDu;  // 0.05f: never spikes
    unsigned hi = 0x3F19999Au;  // 0.6f : spikes at step 1
    while (hi - lo > 1u) {
        unsigned mid = lo + (hi - lo) / 2u;
        if (spikes_by(__builtin_bit_cast(float, mid), p)) hi = mid;
        else lo = mid;
    }
    return hi;
}
constexpr float kB[17] = {
    0.f,
    __builtin_bit_cast(float, find_B(1)),  __builtin_bit_cast(float, find_B(2)),
    __builtin_bit_cast(float, find_B(3)),  __builtin_bit_cast(float, find_B(4)),
    __builtin_bit_cast(float, find_B(5)),  __builtin_bit_cast(float, find_B(6)),
    __builtin_bit_cast(float, find_B(7)),  __builtin_bit_cast(float, find_B(8)),
    __builtin_bit_cast(float, find_B(9)),  __builtin_bit_cast(float, find_B(10)),
    __builtin_bit_cast(float, find_B(11)), __builtin_bit_cast(float, find_B(12)),
    __builtin_bit_cast(float, find_B(13)), __builtin_bit_cast(float, find_B(14)),
    __builtin_bit_cast(float, find_B(15)), __builtin_bit_cast(float, find_B(16))
};
constexpr unsigned mk_train(int F) {
    unsigned tr = 0;
    if (F <= 16) for (int t = F; t <= 16; t += F) tr |= 1u << (t - 1);
    return tr;
}
constexpr unsigned kTv[18] = {
    0, mk_train(1), mk_train(2),  mk_train(3),  mk_train(4),  mk_train(5),
    mk_train(6),  mk_train(7),  mk_train(8),  mk_train(9),  mk_train(10),
    mk_train(11), mk_train(12), mk_train(13), mk_train(14), mk_train(15),
    mk_train(16), mk_train(17)
};

__device__ __forceinline__ unsigned long long tr8(unsigned long long x) {
    unsigned long long t;
    t = (x ^ (x >> 7))  & 0x00AA00AA00AA00AAull; x = x ^ t ^ (t << 7);
    t = (x ^ (x >> 14)) & 0x0000CCCC0000CCCCull; x = x ^ t ^ (t << 14);
    t = (x ^ (x >> 28)) & 0x00000000F0F0F0F0ull; x = x ^ t ^ (t << 28);
    return x;
}

__global__ __launch_bounds__(256, 8) void snn_kernel(
    const float* __restrict__ x,
    const float* __restrict__ W_ih, const float* __restrict__ b_ih,
    const float* __restrict__ W_hh, const float* __restrict__ b_hh,
    const float* __restrict__ W_ho, const float* __restrict__ b_ho,
    float* __restrict__ out, int n)
{
#pragma clang fp contract(off)
    // stride 12 floats = 48 B: 16B-aligned entries, 4-word windows at
    // 12b mod 32 cover all 8 positions as b mod 8 varies (bijection).
    __shared__ __align__(16) float lut2[256 * 12];   // 12 KB
    __shared__ float luto[256];                      // 1 KB
    __shared__ unsigned Tv[18];

    const int p = threadIdx.x;

    {   // lut2 + luto: entry q, neuron k at bit k (LSB), exact fma chains
        float bits[8];
#pragma unroll
        for (int k = 0; k < 8; ++k) bits[k] = (float)((p >> k) & 1);
        float e[8];
#pragma unroll
        for (int j = 0; j < 8; ++j) {
            float acc = 0.f;
#pragma unroll
            for (int k = 0; k < 8; ++k)
                acc = __fmaf_rn(bits[k], W_hh[8 * j + k], acc);
            e[j] = acc;
        }
        float4* dst = reinterpret_cast<float4*>(&lut2[p * 12]);
        dst[0] = make_float4(e[0], e[1], e[2], e[3]);   // 2x b128 writes,
        dst[1] = make_float4(e[4], e[5], e[6], e[7]);   // window-spread
        float acc = 0.f;
#pragma unroll
        for (int k = 0; k < 8; ++k)
            acc = __fmaf_rn(bits[k], W_ho[k], acc);
        luto[p] = acc;
    }
    if (p < 18) Tv[p] = kTv[p];
    __syncthreads();

    const int i = blockIdx.x * 256 + p;
    if (i >= n) return;

    const float2 xv = reinterpret_cast<const float2*>(x)[i];
    float cur[8];
#pragma unroll
    for (int j = 0; j < 8; ++j) {
        float d = __fmaf_rn(xv.y, W_ih[2 * j + 1], __fmul_rn(xv.x, W_ih[2 * j]));
        cur[j] = __fadd_rn(d, b_ih[j]);
    }

    // F = 1 + #{t: c < B_t}; B_t compile-time literals. train = Tv[F]
    unsigned trn[8];
#pragma unroll
    for (int j = 0; j < 8; ++j) {
        float c = cur[j];
        unsigned cnt = 0;
#pragma unroll
        for (int t = 1; t <= 16; ++t)
            cnt += (c < kB[t]) ? 1u : 0u;
        trn[j] = Tv[cnt + 1u];
    }

    // 8x16 bit transpose -> step bytes (byte t = step t, bit j = neuron j)
    unsigned long long A = 0, A2 = 0;
#pragma unroll
    for (int j = 0; j < 8; ++j) {
        A  |= (unsigned long long)(trn[j] & 0xFFu) << (8 * j);
        A2 |= (unsigned long long)((trn[j] >> 8) & 0xFFu) << (8 * j);
    }
    A = tr8(A); A2 = tr8(A2);

    float bh[8];
#pragma unroll
    for (int j = 0; j < 8; ++j) bh[j] = b_hh[j];
    const float bho = b_ho[0];

    float m2[8] = {0.f,0.f,0.f,0.f,0.f,0.f,0.f,0.f};
    float mo = 0.f, odP = 0.f;
    unsigned tot = 0;

    float4 dvlo[2], dvhi[2];

    // prologue: issue dv_0, dv_1 (bytes 0,1; compile-time extracts)
    {
        const unsigned b0 = (unsigned)(A) & 0xFFu;
        const float4* e0 = reinterpret_cast<const float4*>(&lut2[b0 * 12]);
        dvlo[0] = e0[0]; dvhi[0] = e0[1];
        const unsigned b1 = (unsigned)(A >> 8) & 0xFFu;
        const float4* e1 = reinterpret_cast<const float4*>(&lut2[b1 * 12]);
        dvlo[1] = e1[0]; dvhi[1] = e1[1];
    }

    // fully unrolled 16-step pipeline, distance-2 dv prefetch.
    // body t: [consume dv_t | issue dv_{t+2} | mo-update(od_{t-1}) |
    //          issue luto_t]  -> counted lgkm waits, no drains.
#pragma unroll
    for (int t = 0; t < 16; ++t) {
        // consume dv_t (issued 2 bodies ago)
        float dvf[8];
        dvf[0] = dvlo[t & 1].x; dvf[1] = dvlo[t & 1].y;
        dvf[2] = dvlo[t & 1].z; dvf[3] = dvlo[t & 1].w;
        dvf[4] = dvhi[t & 1].x; dvf[5] = dvhi[t & 1].y;
        dvf[6] = dvhi[t & 1].z; dvf[7] = dvhi[t & 1].w;

        unsigned mk2 = 0;
#pragma unroll
        for (int j = 7; j >= 0; --j) {
            float m = __fadd_rn(__fadd_rn(__fmul_rn(0.8f, m2[j]), dvf[j]), bh[j]);
            bool s = (m >= 0.5f);
            mk2 = 2u * mk2 + (s ? 1u : 0u);
            m2[j] = s ? 0.f : m;
        }

        // issue dv_{t+2} into the buffer just consumed (2x ds_read_b128)
        if (t + 2 < 16) {
            const int tn = t + 2;
            const unsigned bN = (tn < 8)
                ? ((unsigned)(A  >> (8 * tn)) & 0xFFu)
                : ((unsigned)(A2 >> (8 * (tn - 8))) & 0xFFu);
            const float4* en = reinterpret_cast<const float4*>(&lut2[bN * 12]);
            dvlo[t & 1] = en[0];
            dvhi[t & 1] = en[1];
        }

        // mo-update for step t-1 (consumes od_{t-1}, issued one body ago)
        if (t > 0) {
            float m = __fadd_rn(__fadd_rn(__fmul_rn(0.8f, mo), odP), bho);
            bool s = (m >= 0.5f);
            tot += s ? 1u : 0u;
            mo = s ? 0.f : m;
        }

        // issue luto_t (consumed in body t+1)
        odP = luto[mk2];
    }
    {   // epilogue: output update for step 15
        float m = __fadd_rn(__fadd_rn(__fmul_rn(0.8f, mo), odP), bho);
        tot += (m >= 0.5f) ? 1u : 0u;
    }

    out[i] = __fmul_rn((float)tot, 0.0625f);
}

extern "C" void kernel_launch(void* const* d_in, const int* in_sizes, int n_in,
                              void* d_out, int out_size, void* d_ws, size_t ws_size,
                              hipStream_t stream) {
    const float* x    = (const float*)d_in[0];
    const float* W_ih = (const float*)d_in[1];
    const float* b_ih = (const float*)d_in[2];
    const float* W_hh = (const float*)d_in[3];
    const float* b_hh = (const float*)d_in[4];
    const float* W_ho = (const float*)d_in[5];
    const float* b_ho = (const float*)d_in[6];
    float* out = (float*)d_out;

    const int n = out_size;  // 524288
    const int block = 256;
    const int grid = (n + block - 1) / block;  // 2048
    snn_kernel<<<grid, block, 0, stream>>>(x, W_ih, b_ih, W_hh, b_hh,
                                           W_ho, b_ho, out, n);
}